// Round 7
// baseline (153.817 us; speedup 1.0000x reference)
//
#include <hip/hip_runtime.h>

// ---------------------------------------------------------------------------
// Q_DenseLayer: BN-fold int8 affine -> ReLU -> per-tensor 8b quant ->
// int8 3x3 conv (MFMA i32_16x16x64_i8) -> per-tensor 8b requant.
// Shapes: x[32,512,32,32] f32, W[128,512,3,3] f32, out y[32,128,32,32] + s_out.
//
// R15: counted-vmcnt + raw-barrier K-loop (T3/T4, m201 discipline). R13/R14
// showed k_conv ~26us = sum-of-pipes; the remaining serializer is
// __syncthreads() = s_waitcnt vmcnt(0) lgkmcnt(0) + s_barrier once per iter:
// all 8 waves/CU drain ALL outstanding VMEM together every iteration.
// New loop (prefetch-distance 2, 2 buffers):
//   A x12 -> B0,B1 ds -> kh0 MFMA -> B2 ds -> kh1 MFMA ->
//   lgkmcnt(0); s_barrier (#1: everyone done READING buf[ci&1]) ->
//   stage ci+2 -> buf[ci&1] (sched_barrier-fenced) -> kh2 MFMA ->
//   vmcnt(9); s_barrier (#2: publish buf[(ci+1)&1], staged LAST iter --
//   a full iteration of latency cover; this iter's 9 stages stay in
//   flight ACROSS the barrier). vmcnt(0) only at ci>=6 (epilogue drain).
// R13/R14 kept: A[4][3] hoist, B0/B1/B2 kh-pipeline, setprio clusters.
// R12 kept: 2x36KB LDS dbuf, wave = 2 rows x 16 w x 64 co (A-reuse 4),
// grid 512 XCD-swizzled, no K-split. Layouts: x2 [b][h][ci8][cq4][w'34][16B],
// wq [tap][ci][cq4][co128][16B]. ~95us harness work outside our control.
// ---------------------------------------------------------------------------

typedef int v4i __attribute__((ext_vector_type(4)));

// workspace byte offsets
#define WS_A1    64        // 512 f: A1_c = w_int*bn_sf/s_in
#define WS_B1    2112      // 512 f: B1_c = b_int*bn_sf
#define WS_WSC   4160      // 128 f
#define WS_XMX   4672      // 512 f: per-channel max(x)
#define WS_XMN   6720      // 512 f: per-channel min(x)
#define WS_WQ    8768      // 589824 i8: [tap][ci][cq][co128][16]
#define WS_X2    598592    // 17825792 u8: [b][h][ci][cq][w'34][16]
#define WS_ZROW  18424384  // 17408 u8 zero row
// ws_f[3] = s_act (k_xquant blk0), ws_u[1] = absmax(y) bits

__device__ __forceinline__ float wave_max(float m) {
#pragma unroll
    for (int off = 32; off; off >>= 1) m = fmaxf(m, __shfl_xor(m, off));
    return m;
}

// async global->LDS, 16B per lane: per-lane gsrc, wave-uniform LDS base
__device__ __forceinline__ void stage16(const char* g, char* s, int lane) {
#if defined(__has_builtin) && __has_builtin(__builtin_amdgcn_global_load_lds)
    __builtin_amdgcn_global_load_lds(
        (const __attribute__((address_space(1))) void*)g,
        (__attribute__((address_space(3))) void*)s, 16, 0, 0);
#else
    *(v4i*)(s + lane * 16) = *(const v4i*)g;
#endif
}

// ---- kernel 1: fused prep ---------------------------------------------------
// blocks 0..511:   per-channel x max/min (block c owns channel c)
// blocks 512..639: conv-weight quant (co = bid-512)
// block 640:       BN fold -> A1/B1, zero y-absmax
__global__ __launch_bounds__(512) void k_prep(
    const float* __restrict__ gamma, const float* __restrict__ beta,
    const float* __restrict__ mean,  const float* __restrict__ var,
    const float* __restrict__ asf,   const float* __restrict__ cw,
    const float4* __restrict__ x4,
    float* ws_f, unsigned* ws_u, float* __restrict__ wsc,
    signed char* __restrict__ wq) {
    int t = threadIdx.x;
    int bid = blockIdx.x;
    __shared__ float red[16];
    if (bid < 512) {
        int c = bid;
        float mx = -3.4e38f, mn = 3.4e38f;
#pragma unroll
        for (int r = 0; r < 16; ++r) {
            int bbb = r * 2 + (t >> 8);
            float4 v = x4[((size_t)(bbb * 512 + c)) * 256 + (t & 255)];
            mx = fmaxf(mx, fmaxf(fmaxf(v.x, v.y), fmaxf(v.z, v.w)));
            mn = fminf(mn, fminf(fminf(v.x, v.y), fminf(v.z, v.w)));
        }
        mx = wave_max(mx);
        mn = -wave_max(-mn);
        if ((t & 63) == 0) { red[t >> 6] = mx; red[8 + (t >> 6)] = mn; }
        __syncthreads();
        if (t == 0) {
            float M = red[0], N = red[8];
#pragma unroll
            for (int i = 1; i < 8; ++i) { M = fmaxf(M, red[i]); N = fminf(N, red[8 + i]); }
            ws_f[WS_XMX / 4 + c] = M;
            ws_f[WS_XMN / 4 + c] = N;
        }
    } else if (bid < 640) {
        int co = bid - 512;
        const float* w = cw + (size_t)co * 4608;
        float m = 0.f;
        for (int j = t; j < 4608; j += 512) m = fmaxf(m, fabsf(w[j]));
        m = wave_max(m);
        if ((t & 63) == 0) red[t >> 6] = m;
        __syncthreads();
        float mall = red[0];
#pragma unroll
        for (int i = 1; i < 8; ++i) mall = fmaxf(mall, red[i]);
        float sc = mall / 127.0f;
        if (t == 0) wsc[co] = sc;
        int ci = t >> 6, cq = (t >> 4) & 3, cb = t & 15;
#pragma unroll
        for (int tap = 0; tap < 9; ++tap) {
            float q = fminf(fmaxf(rintf(w[t * 9 + tap] / sc), -128.f), 127.f);
            wq[(((size_t)(tap * 8 + ci) * 4 + cq) * 128 + co) * 16 + cb] = (signed char)q;
        }
    } else {
        float wbn = gamma[t] / sqrtf(var[t] + 1e-5f);
        float bbn = beta[t] - mean[t] * wbn;
        float m = wave_max(fabsf(wbn));
        if ((t & 63) == 0) red[t >> 6] = m;
        __syncthreads();
        float mall = red[0];
#pragma unroll
        for (int i = 1; i < 8; ++i) mall = fmaxf(mall, red[i]);
        float ws_bn = mall / 127.0f;
        float s_in  = asf[0];
        float bn_sf = ws_bn * s_in;
        float wint  = fminf(fmaxf(rintf(wbn / ws_bn), -128.f), 127.f);
        float bint  = rintf(bbn / bn_sf);
        ws_f[WS_A1 / 4 + t] = wint * bn_sf / s_in;  // x1 = fmaf(x, A1, B1)
        ws_f[WS_B1 / 4 + t] = bint * bn_sf;
        if (t == 0) ws_u[1] = 0u;  // absmax(y) bits
    }
}

// ---- kernel 2: quantize x to int8 [ci][cq][w'][16] halo layout -------------
__global__ __launch_bounds__(256) void k_xquant(
    const float4* __restrict__ x4, float* __restrict__ ws_f,
    unsigned* __restrict__ x2u, unsigned* __restrict__ zrowu) {
    int bb = 31 - (blockIdx.x >> 5), h = blockIdx.x & 31;
    const float* A1 = ws_f + WS_A1 / 4;
    const float* B1 = ws_f + WS_B1 / 4;
    const float* XMX = ws_f + WS_XMX / 4;
    const float* XMN = ws_f + WS_XMN / 4;
    int t = threadIdx.x;

    // s_act from per-channel stats (exact: fma monotone in x, relu clamp >=0)
    __shared__ float sred[4];
    float cand = 0.f;
#pragma unroll
    for (int c0 = 0; c0 < 512; c0 += 256) {
        int c = c0 + t;
        float A = A1[c], B = B1[c];
        cand = fmaxf(cand, fmaxf(fmaf(XMX[c], A, B), fmaf(XMN[c], A, B)));
    }
    cand = wave_max(cand);
    if ((t & 63) == 0) sred[t >> 6] = cand;
    __syncthreads();
    float xm = fmaxf(fmaxf(sred[0], sred[1]), fmaxf(sred[2], sred[3]));
    float inv_sact = 127.0f / xm;
    if (blockIdx.x == 0 && t == 0) ws_f[3] = xm / 127.0f;  // s_act for k_conv

    size_t rowd = (size_t)(bb * 32 + h) * 4352;  // dwords per (b,h) row
    // zero halo columns w'=0,33
    {
        int p = t >> 3, side = (t >> 2) & 1, d = t & 3;
        x2u[rowd + (p * 34 + side * 33) * 4 + d] = 0u;
    }
    if (blockIdx.x < 17) {
        int idx = blockIdx.x * 256 + t;
        if (idx < 4352) zrowu[idx] = 0u;
    }

    __shared__ unsigned lds[512 * 9];  // [c][w4(8)] packed bytes, +1 pad

#pragma unroll
    for (int it = 0; it < 16; ++it) {
        int idx = it * 256 + t;
        int c = idx >> 3, f4 = idx & 7;
        float4 v = x4[((size_t)bb * 512 + c) * 256 + h * 8 + f4];
        float A = A1[c] * inv_sact, B = B1[c] * inv_sact;
        unsigned q0 = (unsigned)(int)fminf(rintf(fmaxf(fmaf(v.x, A, B), 0.f)), 127.f);
        unsigned q1 = (unsigned)(int)fminf(rintf(fmaxf(fmaf(v.y, A, B), 0.f)), 127.f);
        unsigned q2 = (unsigned)(int)fminf(rintf(fmaxf(fmaf(v.z, A, B), 0.f)), 127.f);
        unsigned q3 = (unsigned)(int)fminf(rintf(fmaxf(fmaf(v.w, A, B), 0.f)), 127.f);
        lds[c * 9 + f4] = q0 | (q1 << 8) | (q2 << 16) | (q3 << 24);
    }
    __syncthreads();

#pragma unroll
    for (int it = 0; it < 4; ++it) {
        int p = it * 8 + (t >> 5);   // 0..31 = ci*4+cq
        int s = (t >> 2) & 7;        // w4 group
        int k = t & 3;               // w = s*4+k, w' = w+1
        unsigned L[16];
#pragma unroll
        for (int j = 0; j < 16; ++j) L[j] = lds[(p * 16 + j) * 9 + s];
        uint4 o;
        unsigned* op = (unsigned*)&o;
#pragma unroll
        for (int d = 0; d < 4; ++d)
            op[d] = ((L[4 * d] >> (8 * k)) & 255u) |
                    (((L[4 * d + 1] >> (8 * k)) & 255u) << 8) |
                    (((L[4 * d + 2] >> (8 * k)) & 255u) << 16) |
                    (((L[4 * d + 3] >> (8 * k)) & 255u) << 24);
        *(uint4*)(x2u + rowd + (size_t)(p * 34 + s * 4 + 1 + k) * 4) = o;
    }
}

// ---- kernel 3: int8 3x3 conv, counted-vmcnt raw-barrier pipeline -----------
// block = 4 rows x 64 co, 4 waves = (rp row-pair, wh w-half);
// wave = 2 rows x 16 w x 64 co, acc[2][4]. Prefetch-distance 2, 2 buffers:
// iter ci reads buf[ci&1], stages ci+2 into buf[ci&1] after barrier #1.
// Barriers are raw s_barrier with counted vmcnt -- never drain to 0 in
// steady state, so stage loads stay in flight ACROSS barriers and get a
// full iteration of latency cover. LDS 2x36KB=72KB -> 2 blocks/CU.
__global__ __launch_bounds__(256, 2) void k_conv(
    const unsigned char* __restrict__ x2, const unsigned char* __restrict__ zrow,
    const signed char* __restrict__ wq,
    const float* __restrict__ wsc, const float* __restrict__ ws_f,
    unsigned* __restrict__ amaxy, float* __restrict__ y) {
    __shared__ char ldsb[73728];
    int t = threadIdx.x;
    int lane = t & 63, wv = t >> 6;
    int wh = wv & 1, rp = wv >> 1;   // w-half, row-pair
    int m = lane & 15, quad = lane >> 4;

    int bid = blockIdx.x;
    int tile = (bid & 7) * 64 + (bid >> 3);  // XCD swizzle, 64 tiles/XCD
    int ch = tile & 1;
    int rg = (tile >> 1) & 7;                // row-group of 4 rows
    int bb = tile >> 4;
    int co0 = ch * 64;
    int h0 = rg * 4 + rp * 2;                // this wave's first output row

    const unsigned char* xb = x2 + (size_t)bb * (32 * 17408);
    const v4i* rpt[4];
#pragma unroll
    for (int j = 0; j < 4; ++j) {
        int row = h0 - 1 + j;
        rpt[j] = (const v4i*)(((unsigned)row < 32u) ? (xb + (size_t)row * 17408) : zrow);
    }

    v4i acc[2][4];
#pragma unroll
    for (int i = 0; i < 2; ++i)
#pragma unroll
        for (int j = 0; j < 4; ++j) acc[i][j] = (v4i){0, 0, 0, 0};

    int abase = quad * 34 + m + wh * 16;  // [cq=quad][w'=m+wh*16] in v4i units

    auto stage_ci = [&](int cig, int buf) {
#pragma unroll
        for (int i = 0; i < 9; ++i) {
            int c = wv * 9 + i;
            int tap = c >> 2, cq = c & 3;
            const char* g = (const char*)wq +
                ((((size_t)(tap * 8 + cig) * 4 + cq) * 128 + co0) * 16) + lane * 16;
            stage16(g, ldsb + buf * 36864 + (c << 10), lane);
        }
    };

    // prologue: stage ci=0 -> buf0, ci=1 -> buf1; publish buf0 (vmcnt(9):
    // stage0 retired, stage1 may stay in flight until iter-0's barrier #2).
    stage_ci(0, 0);
    stage_ci(1, 1);
    asm volatile("s_waitcnt vmcnt(9)" ::: "memory");
    __builtin_amdgcn_s_barrier();

#pragma unroll
    for (int ci = 0; ci < 8; ++ci) {
        const v4i* bv = (const v4i*)(ldsb + (ci & 1) * 36864);

        // A-loads (12 global): consumed by this iter's MFMAs.
        v4i A[4][3];
#pragma unroll
        for (int r = 0; r < 4; ++r)
#pragma unroll
            for (int kw = 0; kw < 3; ++kw)
                A[r][kw] = rpt[r][ci * 136 + abase + kw];

        auto load_B = [&](v4i(&B)[3][4], int kh) {
#pragma unroll
            for (int kw = 0; kw < 3; ++kw)
#pragma unroll
                for (int nt = 0; nt < 4; ++nt)
                    B[kw][nt] = bv[((kh * 3 + kw) * 4 + quad) * 64 + nt * 16 + m];
        };
        auto mfma_kh = [&](const v4i(&Ar0)[3], const v4i(&Ar1)[3],
                           const v4i(&B)[3][4]) {
            __builtin_amdgcn_s_setprio(1);
#pragma unroll
            for (int kw = 0; kw < 3; ++kw)
#pragma unroll
                for (int nt = 0; nt < 4; ++nt) {
                    acc[0][nt] = __builtin_amdgcn_mfma_i32_16x16x64_i8(
                        Ar0[kw], B[kw][nt], acc[0][nt], 0, 0, 0);
                    acc[1][nt] = __builtin_amdgcn_mfma_i32_16x16x64_i8(
                        Ar1[kw], B[kw][nt], acc[1][nt], 0, 0, 0);
                }
            __builtin_amdgcn_s_setprio(0);
        };

        v4i B0[3][4], B1[3][4], B2[3][4];
        load_B(B0, 0);
        load_B(B1, 1);
        mfma_kh(A[0], A[1], B0);
        load_B(B2, 2);
        mfma_kh(A[1], A[2], B1);

        // barrier #1: all my ds_reads of buf[ci&1] are retired (B2 in regs);
        // after the barrier everyone is done reading -> safe to overwrite.
        asm volatile("s_waitcnt lgkmcnt(0)" ::: "memory");
        __builtin_amdgcn_s_barrier();
        __builtin_amdgcn_sched_barrier(0);
        if (ci < 6) stage_ci(ci + 2, ci & 1);
        __builtin_amdgcn_sched_barrier(0);

        mfma_kh(A[2], A[3], B2);

        // barrier #2: publish buf[(ci+1)&1] (staged LAST iter). vmcnt(9)
        // retires last iter's stage while THIS iter's 9 stay in flight.
        // ci>=6: no new stages issued -> drain fully (epilogue).
        if (ci < 6)
            asm volatile("s_waitcnt vmcnt(9)" ::: "memory");
        else
            asm volatile("s_waitcnt vmcnt(0)" ::: "memory");
        __builtin_amdgcn_s_barrier();
    }

    // epilogue: C layout col(lane&15)=co, row(quad*4+reg)=w-within-half.
    // y unquantized; track block absmax -> one atomicMax per block.
    float s_act = ws_f[3];
    float mx = 0.f;
#pragma unroll
    for (int nt = 0; nt < 4; ++nt) {
        int co = co0 + nt * 16 + m;
        float sf = s_act * wsc[co];
#pragma unroll
        for (int r = 0; r < 2; ++r) {
            int row = h0 + r;
            float* yb = y + ((size_t)(bb * 128 + co)) * 1024 + row * 32 + wh * 16;
            float4 vv;
            vv.x = (float)acc[r][nt][0] * sf;
            vv.y = (float)acc[r][nt][1] * sf;
            vv.z = (float)acc[r][nt][2] * sf;
            vv.w = (float)acc[r][nt][3] * sf;
            *(float4*)(yb + quad * 4) = vv;
            mx = fmaxf(mx, fmaxf(fmaxf(fabsf(vv.x), fabsf(vv.y)),
                                 fmaxf(fabsf(vv.z), fabsf(vv.w))));
        }
    }
    mx = wave_max(mx);
    if (lane == 0) ((float*)ldsb)[wv] = mx;   // loop ended with full drain
    __syncthreads();
    if (t == 0) {
        float* r = (float*)ldsb;
        float M = fmaxf(fmaxf(r[0], r[1]), fmaxf(r[2], r[3]));
        atomicMax(amaxy, __float_as_uint(M));
    }
}

// ---- kernel 4: final requant in place + write s_out -----------------------
__global__ __launch_bounds__(256) void k_yquant(float* __restrict__ yout,
                                                const unsigned* __restrict__ ws_u) {
    float s_out = __uint_as_float(ws_u[1]) / 127.0f;
    float4* y4 = (float4*)yout;
    int stride = gridDim.x * blockDim.x;
    for (int i = blockIdx.x * blockDim.x + threadIdx.x; i < 1048576; i += stride) {
        float4 v = y4[i];
        v.x = fminf(fmaxf(rintf(v.x / s_out), -128.f), 127.f) * s_out;
        v.y = fminf(fmaxf(rintf(v.y / s_out), -128.f), 127.f) * s_out;
        v.z = fminf(fmaxf(rintf(v.z / s_out), -128.f), 127.f) * s_out;
        v.w = fminf(fmaxf(rintf(v.w / s_out), -128.f), 127.f) * s_out;
        y4[i] = v;
    }
    if (blockIdx.x == 0 && threadIdx.x == 0) yout[4194304] = s_out;
}

extern "C" void kernel_launch(void* const* d_in, const int* in_sizes, int n_in,
                              void* d_out, int out_size, void* d_ws, size_t ws_size,
                              hipStream_t stream) {
    const float* x     = (const float*)d_in[0];
    const float* asf   = (const float*)d_in[1];
    const float* gamma = (const float*)d_in[2];
    const float* beta  = (const float*)d_in[3];
    const float* mean  = (const float*)d_in[4];
    const float* var   = (const float*)d_in[5];
    const float* cw    = (const float*)d_in[6];

    float*    ws_f = (float*)d_ws;
    unsigned* ws_u = (unsigned*)d_ws;
    signed char*   wq   = (signed char*)d_ws + WS_WQ;
    unsigned char* x2   = (unsigned char*)d_ws + WS_X2;
    unsigned char* zrow = (unsigned char*)d_ws + WS_ZROW;
    float* y = (float*)d_out;

    k_prep<<<641, 512, 0, stream>>>(gamma, beta, mean, var, asf, cw,
                                    (const float4*)x, ws_f, ws_u,
                                    ws_f + WS_WSC / 4, wq);
    k_xquant<<<1024, 256, 0, stream>>>((const float4*)x, ws_f,
                                       (unsigned*)x2, (unsigned*)zrow);
    k_conv<<<512, 256, 0, stream>>>(x2, zrow, wq, ws_f + WS_WSC / 4,
                                    ws_f, ws_u + 1, y);
    k_yquant<<<1024, 256, 0, stream>>>(y, ws_u);
}